// Round 12
// baseline (985.665 us; speedup 1.0000x reference)
//
#include <hip/hip_runtime.h>
#include <stdint.h>

// RPN RoI proposal, 4-kernel pipeline -- R12 INSTRUMENTED BUILD.
// Identical algorithm to R11 (passing, absmax 0). Each kernel's compute body
// is repeated REP_* times (idempotent: identical stores each rep) so every
// kernel's duration exceeds the ~53us harness-fill floor and surfaces in the
// rocprof top-5 with Start/End timestamps. Diagnosis targets:
//   dur/REP = true kernel cost; Start[i+1]-End[i] = node boundary overhead.
// REP will revert to 1 next round once the 40us mystery is located.

#define PRE 2000
#define POST 300
#define TILE 512
#define IOU_THR 0.7f
#define EPSV 1e-8f
#define SORTN 2048
#define NBINS 2048
#define DESTCAP 4096
#define CANDCAP 512
#define CONS 1984
#define SL 16
#define KBUF 768

#define REP_K1 16
#define REP_K2 8
#define REP_K4 16
#define REP_K5 16

typedef unsigned long long u64;

__device__ __forceinline__ uint32_t flip_f32(uint32_t b) {
    return b ^ ((uint32_t)((int32_t)b >> 31) | 0x80000000u);
}

__device__ __forceinline__ int bin_of(float s) {
    int bn = (int)(s * 2048.0f);
    return min(max(bn, 0), NBINS - 1);
}

__device__ __forceinline__ u64 make_key(float s, int idx, int bn) {
    uint32_t ub = flip_f32(__float_as_uint(s));
    return ((u64)ub << 32) | ((uint32_t)bn << 20) |
           (uint32_t)(0xFFFFF - idx);
}

__device__ __forceinline__ bool iou_gt(const float4& bi, float ai,
                                       const float4& bj, float aj) {
    float yy1 = fmaxf(bi.x, bj.x);
    float xx1 = fmaxf(bi.y, bj.y);
    float yy2 = fminf(bi.z, bj.z);
    float xx2 = fminf(bi.w, bj.w);
    float inter = fmaxf(yy2 - yy1, 0.f) * fmaxf(xx2 - xx1, 0.f);
    float iou = inter / (ai + aj - inter + EPSV);
    return iou > IOU_THR;
}

__device__ __forceinline__ float area_of(const float4& bx) {
    return fmaxf(bx.z - bx.x, 0.f) * fmaxf(bx.w - bx.y, 0.f);
}

__device__ __forceinline__ u64 cs_keep(u64 v, u64 pv, int i, int j, int k) {
    bool lower   = ((i & j) == 0);
    bool desc    = ((i & k) == 0);
    bool keepmax = (desc == lower);
    u64 mx = v > pv ? v : pv;
    u64 mn = v > pv ? pv : v;
    return keepmax ? mx : mn;
}

// ---------------- K1: pure threshold gather --------------------------------
__global__ __launch_bounds__(256) void k1_gather(
    const float4* __restrict__ score4,
    u64* __restrict__ g_pairs,           // [B*SL*KBUF]
    int* __restrict__ g_scnt,            // [B*SL] raw counts
    int N)
{
    const int blk = blockIdx.x;
    const int b   = blk / SL;
    const int s   = blk % SL;
    const int tid = threadIdx.x;
    const int F4PB = N >> 2;
    const int F4PS = (F4PB + SL - 1) / SL;

    __shared__ u64 keybuf[KBUF];
    __shared__ int kcnt;

    for (int rep = 0; rep < REP_K1; ++rep) {
        if (tid == 0) kcnt = 0;
        __syncthreads();

        const float4* src = score4 + (size_t)b * F4PB;
        const int n0 = s * F4PS, n1 = min(n0 + F4PS, F4PB);
        for (int n = n0 + tid; n < n1; n += 256) {
            float4 v = src[n];
            float sv[4] = {v.x, v.y, v.z, v.w};
#pragma unroll
            for (int c = 0; c < 4; ++c) {
                int bn = bin_of(sv[c]);
                if (bn >= CONS) {
                    int q = atomicAdd(&kcnt, 1);
                    if (q < KBUF) keybuf[q] = make_key(sv[c], 4 * n + c, bn);
                }
            }
        }
        __syncthreads();

        if (tid == 0) g_scnt[b * SL + s] = kcnt;
        int lc = min(kcnt, KBUF);
        u64* gp = g_pairs + ((size_t)b * SL + s) * KBUF;
        for (int i = tid; i < lc; i += 256) gp[i] = keybuf[i];
        __syncthreads();
    }
}

// ---------------- K2: superset sort + decode + supT ------------------------
__global__ __launch_bounds__(1024) void k2_sort(
    const float4* __restrict__ score4,
    const u64*  __restrict__ g_pairs,
    const int*  __restrict__ g_scnt,
    const float4* __restrict__ deltas,
    const float4* __restrict__ anchors,
    float4* __restrict__ g_boxes,
    float*  __restrict__ g_area,
    uint32_t* __restrict__ g_supT,       // [B*512*2] diag col-words
    int N)
{
    const int b    = blockIdx.x;
    const int tid  = threadIdx.x;
    const int lane = tid & 63;
    const int wv   = tid >> 6;

    __shared__ u64 dest[DESTCAP];
    __shared__ float4 sbox[TILE];        // first-512 boxes; fallback hist2048
    __shared__ u64 cand[CANDCAP];
    __shared__ uint32_t hist64[64];
    __shared__ int segbase64[64];
    __shared__ uint32_t cur64[64];
    __shared__ int scnt_s[SL];
    __shared__ uint32_t wtot[16];
    __shared__ int sh_flag, sh_total, sh_bsel, sh_tprime, sh_cnt, sh_nc;
    __shared__ uint32_t sh_pivot;

    const int F4PB = N >> 2;

    for (int rep = 0; rep < REP_K2; ++rep) {

    if (tid < SL) scnt_s[tid] = g_scnt[b * SL + tid];
    if (tid < 64) { hist64[tid] = 0u; cur64[tid] = 0u; }
    if (tid == 0) { sh_flag = 0; sh_cnt = 0; sh_nc = 0; }
    __syncthreads();

    // pass 1: 64-bin hist from keys (wave wv handles slice wv)
    {
        int raw = scnt_s[wv];
        if (raw > KBUF) sh_flag = 1;
        int cs = min(raw, KBUF);
        const u64* gp = g_pairs + ((size_t)b * SL + wv) * KBUF;
        for (int i = lane; i < cs; i += 64) {
            int b64 = (int)((gp[i] >> 20) & 0xFFFu) - CONS;
            atomicAdd(&hist64[b64], 1u);
        }
    }
    __syncthreads();

    // 1-wave suffix scan of 64 bins
    if (wv == 0) {
        int h = (int)hist64[lane];
        int ssum = h;
#pragma unroll
        for (int off = 1; off < 64; off <<= 1) {
            int t = __shfl_down(ssum, off, 64);
            if (lane + off < 64) ssum += t;
        }
        segbase64[lane] = ssum - h;
        if (lane == 0) sh_total = ssum;
        if (h > 128) sh_flag = 1;
    }
    __syncthreads();
    const int total = sh_total;
    if (tid == 0 && (total < PRE || total > DESTCAP)) sh_flag = 1;
    __syncthreads();
    const bool flag = (sh_flag != 0);

    if (!flag) {
        // pass 2: counting-scatter to bin segments
        int cs = min(scnt_s[wv], KBUF);
        const u64* gp = g_pairs + ((size_t)b * SL + wv) * KBUF;
        for (int i = lane; i < cs; i += 64) {
            u64 key = gp[i];
            int b64 = (int)((key >> 20) & 0xFFFu) - CONS;
            int c = (int)atomicAdd(&cur64[b64], 1u);
            dest[segbase64[b64] + c] = key;
        }
        __syncthreads();
        // per-wave segment sorts (zero barriers)
        for (int sgi = wv; sgi < 64; sgi += 16) {
            int n = (int)cur64[sgi];
            if (n <= 0) continue;
            int base = segbase64[sgi];
            if (n <= 64) {
                u64 e = (lane < n) ? dest[base + lane] : 0ull;
#pragma unroll
                for (int k = 2; k <= 64; k <<= 1)
                    for (int j = k >> 1; j > 0; j >>= 1)
                        e = cs_keep(e, __shfl_xor(e, j, 64), lane, j, k);
                if (lane < n) dest[base + lane] = e;
            } else {
                u64 e0 = (lane < n) ? dest[base + lane] : 0ull;
                u64 e1 = (lane + 64 < n) ? dest[base + lane + 64] : 0ull;
#pragma unroll
                for (int k = 2; k <= 128; k <<= 1) {
                    for (int j = k >> 1; j > 0; j >>= 1) {
                        if (j == 64) {
                            u64 a = e0, c = e1;
                            e0 = cs_keep(a, c, lane, 64, k);
                            e1 = cs_keep(c, a, lane + 64, 64, k);
                        } else {
                            e0 = cs_keep(e0, __shfl_xor(e0, j, 64), lane, j, k);
                            e1 = cs_keep(e1, __shfl_xor(e1, j, 64), lane + 64, j, k);
                        }
                    }
                }
                if (lane < n) dest[base + lane] = e0;
                if (lane + 64 < n) dest[base + lane + 64] = e1;
            }
        }
        __syncthreads();
    } else {
        // exact fallback: hist-based top-2000 (never taken on this data)
        uint32_t* hist = (uint32_t*)sbox;
        hist[tid] = 0u; hist[tid + 1024] = 0u;
        if (tid == 0) { sh_cnt = 0; sh_nc = 0; }
        __syncthreads();
        const float4* src = score4 + (size_t)b * F4PB;
        for (int n = tid; n < F4PB; n += 1024) {
            float4 v = src[n];
            atomicAdd(&hist[bin_of(v.x)], 1u);
            atomicAdd(&hist[bin_of(v.y)], 1u);
            atomicAdd(&hist[bin_of(v.z)], 1u);
            atomicAdd(&hist[bin_of(v.w)], 1u);
        }
        __syncthreads();
        {
            const int i0 = wv * 128 + lane;
            const int i1 = i0 + 64;
            int h0 = (int)hist[i0];
            int h1 = (int)hist[i1];
            int s0 = h0, s1 = h1;
#pragma unroll
            for (int off = 1; off < 64; off <<= 1) {
                int t0 = __shfl_down(s0, off, 64);
                int t1 = __shfl_down(s1, off, 64);
                if (lane + off < 64) { s0 += t0; s1 += t1; }
            }
            int sum_h1 = __shfl(s1, 0, 64);
            if (lane == 0) wtot[wv] = (uint32_t)(__shfl(s0, 0, 64) + sum_h1);
            __syncthreads();
            int offtot = 0;
            for (int w2 = wv + 1; w2 < 16; ++w2) offtot += (int)wtot[w2];
            int S0 = s0 + sum_h1 + offtot;
            int S1 = s1 + offtot;
            if (S0 >= PRE && S0 - h0 < PRE) { sh_bsel = i0; sh_tprime = PRE - (S0 - h0); }
            if (S1 >= PRE && S1 - h1 < PRE) { sh_bsel = i1; sh_tprime = PRE - (S1 - h1); }
        }
        __syncthreads();
        const int bsel   = sh_bsel;
        const int tprime = sh_tprime;
        __syncthreads();
        for (int n = tid; n < F4PB; n += 1024) {
            float4 v = src[n];
            float sv[4] = {v.x, v.y, v.z, v.w};
#pragma unroll
            for (int c = 0; c < 4; ++c) {
                int bn = bin_of(sv[c]);
                if (bn >= bsel) {
                    u64 key = make_key(sv[c], 4 * n + c, bn);
                    if (bn > bsel) {
                        int q = atomicAdd(&sh_cnt, 1);
                        if (q < SORTN) dest[q] = key;
                    } else {
                        int t = atomicAdd(&sh_nc, 1);
                        if (t < CANDCAP) cand[t] = key;
                    }
                }
            }
        }
        __syncthreads();
        const int nc = min(sh_nc, CANDCAP);
        for (int i = tid; i < nc; i += 1024) {
            uint32_t vi = (uint32_t)(cand[i] >> 32);
            int g = 0, e = 0;
            for (int j = 0; j < nc; ++j) {
                uint32_t vj = (uint32_t)(cand[j] >> 32);
                g += (vj > vi);
                e += (vj == vi);
            }
            if (g < tprime && g + e >= tprime) sh_pivot = vi;
        }
        __syncthreads();
        const uint32_t pivot = sh_pivot;
        for (int i = tid; i < nc; i += 1024) {
            uint32_t vi = (uint32_t)(cand[i] >> 32);
            if (vi >= pivot) {
                int q = atomicAdd(&sh_cnt, 1);
                if (q < SORTN) dest[q] = cand[i];
            }
        }
        __syncthreads();
        const int tt = min(sh_cnt, SORTN);
        for (int q = tt + tid; q < SORTN; q += 1024) dest[q] = 0ull;
        __syncthreads();
        {
            const int i0 = wv * 128 + lane;
            const int i1 = i0 + 64;
            u64 e0 = dest[i0];
            u64 e1 = dest[i1];
            for (int k = 2; k <= SORTN; k <<= 1) {
                for (int j = k >> 1; j > 0; j >>= 1) {
                    if (j >= 128) {
                        dest[i0] = e0;
                        dest[i1] = e1;
                        __syncthreads();
                        u64 p0 = dest[i0 ^ j];
                        u64 p1 = dest[i1 ^ j];
                        __syncthreads();
                        e0 = cs_keep(e0, p0, i0, j, k);
                        e1 = cs_keep(e1, p1, i1, j, k);
                    } else if (j == 64) {
                        u64 a = e0, c = e1;
                        e0 = cs_keep(a, c, i0, 64, k);
                        e1 = cs_keep(c, a, i1, 64, k);
                    } else {
                        e0 = cs_keep(e0, __shfl_xor(e0, j, 64), i0, j, k);
                        e1 = cs_keep(e1, __shfl_xor(e1, j, 64), i1, j, k);
                    }
                }
            }
            dest[i0] = e0;
            dest[i1] = e1;
        }
        __syncthreads();
    }

    // fused decode of top-2000 (stash first 512 boxes in LDS)
    const float4* dl = deltas + (size_t)b * N;
    for (int r = tid; r < PRE; r += 1024) {
        u64 key = dest[r];
        uint32_t idx = 0xFFFFFu - (uint32_t)(key & 0xFFFFFull);
        float4 bx = make_float4(0.f, 0.f, 0.f, 0.f);
        float  ar = 0.f;
        if (idx < (uint32_t)N) {
            float4 d  = dl[idx];
            float4 an = anchors[idx];
            float ah  = an.z - an.x;
            float aw  = an.w - an.y;
            float acy = an.x + 0.5f * ah;
            float acx = an.y + 0.5f * aw;
            float h   = expf(d.z) * ah;
            float w   = expf(d.w) * aw;
            float cy  = d.x * ah + acy;
            float cx  = d.y * aw + acx;
            float y1  = cy - 0.5f * h;
            float x1  = cx - 0.5f * w;
            bx = make_float4(y1, x1, y1 + h, x1 + w);
            ar = fmaxf(bx.z - bx.x, 0.f) * fmaxf(bx.w - bx.y, 0.f);
        }
        g_boxes[(size_t)b * PRE + r] = bx;
        g_area [(size_t)b * PRE + r] = ar;
        if (r < TILE) sbox[r] = bx;
    }
    __syncthreads();

    // fused supT: 8 chunks x 64 cols x 2 words = 1024 tasks
    {
        int q  = tid >> 7;
        int j  = (tid >> 1) & 63;
        int w2 = tid & 1;
        int C  = q * 64 + j;
        float4 bc = sbox[C];
        float  ac = area_of(bc);
        uint32_t bits = 0u;
#pragma unroll
        for (int c = 0; c < 32; ++c) {
            int R = q * 64 + w2 * 32 + c;
            float4 br = sbox[R];
            float  ar = area_of(br);
            bool gt = (R < C) & iou_gt(br, ar, bc, ac);
            bits |= ((uint32_t)gt) << c;
        }
        g_supT[((size_t)b * TILE + C) * 2 + w2] = bits;
    }
    __syncthreads();

    } // rep
}

// ---------------- K4: suppression matrix (high-occupancy) ------------------
__global__ __launch_bounds__(256) void k4_supmat(
    const float4* __restrict__ g_boxes,
    uint32_t* __restrict__ g_supmat)     // [B*512*16] row-major
{
    const int b   = blockIdx.x >> 4;
    const int s   = blockIdx.x & 15;
    const int tid = threadIdx.x;

    __shared__ float4 box[TILE];
    for (int i = tid; i < TILE; i += 256)
        box[i] = g_boxes[(size_t)b * PRE + i];
    __syncthreads();

    const int rbase = s * 32;
    for (int rep = 0; rep < REP_K4; ++rep) {
#pragma unroll
        for (int k = 0; k < 2; ++k) {
            int idx = tid + k * 256;
            int row = rbase + (idx & 31);
            int w   = idx >> 5;
            int jbase = w << 5;
            float4 bi = box[row];
            float  ai = area_of(bi);
            uint32_t bits = 0u;
            if (jbase + 31 > row) {
#pragma unroll
                for (int c = 0; c < 32; ++c) {
                    int j = jbase + c;
                    float4 bj = box[j];
                    float  aj = area_of(bj);
                    bool gt = (j > row) & iou_gt(bi, ai, bj, aj);
                    bits |= ((uint32_t)gt) << c;
                }
            }
            g_supmat[((size_t)b * TILE + row) * 16 + w] = bits;
        }
        __syncthreads();
    }
}

// ---------------- K5: ballot-resolve chunked greedy sweep ------------------
__global__ __launch_bounds__(64) void k5_sweep(
    const uint32_t* __restrict__ g_supmat,
    const u64*    __restrict__ g_supT64,   // [B*512] diag col-words
    const float4* __restrict__ g_boxes,
    const float*  __restrict__ g_area,
    float4* __restrict__ out)
{
    const int b    = blockIdx.x;
    const int lane = threadIdx.x;

    __shared__ uint32_t kept[POST];
    __shared__ u64 sh_keepbits[TILE / 64];
    __shared__ uint32_t fmask[(PRE - TILE + 31) / 32];
    __shared__ int sh_kc;

    const u64* tdbase = g_supT64 + (size_t)b * TILE;

    for (int rep = 0; rep < REP_K5; ++rep) {

    uint32_t removedw = 0u;
    int kc = 0, nq = 0;
    u64 cw_cur = tdbase[lane];
    for (int q = 0; q < TILE / 64; ++q) {
        u64 cw_next = (q < TILE / 64 - 1) ? tdbase[(q + 1) * 64 + lane] : 0ull;
        const int cbase = q << 6;
        uint32_t rlo = (uint32_t)__builtin_amdgcn_readlane((int)removedw, 2 * q);
        uint32_t rhi = (uint32_t)__builtin_amdgcn_readlane((int)removedw, 2 * q + 1);
        u64 avail = ~(((u64)rhi << 32) | rlo);
        u64 K = 0ull;
        while (avail) {
            int i = __ffsll((long long)avail) - 1;
            K |= (1ull << i);
            u64 supp = __ballot(((cw_cur >> i) & 1ull) != 0ull);
            avail &= ~(supp | (1ull << i));
        }
        if (lane == 0) sh_keepbits[q] = K;
        kc += __popcll(K);
        nq = q + 1;
        if (kc >= POST) break;
        if (K) {
            const int w = lane & 15;
            const int g = lane >> 4;
            const uint32_t* gs =
                g_supmat + ((size_t)b * TILE + cbase + g * 16) * 16 + w;
            uint32_t acc = 0u;
#pragma unroll
            for (int r = 0; r < 16; ++r)
                if ((K >> (g * 16 + r)) & 1ull) acc |= gs[(size_t)r * 16];
            acc |= (uint32_t)__shfl_xor((int)acc, 16, 64);
            acc |= (uint32_t)__shfl_xor((int)acc, 32, 64);
            if (lane < 16) removedw |= acc;
        }
        cw_cur = cw_next;
    }
    {
        int base = 0;
        for (int q = 0; q < nq; ++q) {
            u64 kbq = sh_keepbits[q];
            int pos = base + __popcll(kbq & ((1ull << lane) - 1));
            if (((kbq >> lane) & 1ull) && pos < POST)
                kept[pos] = (uint32_t)(q * 64 + lane);
            base += __popcll(kbq);
        }
        if (lane == 0) sh_kc = min(kc, POST);
    }
    __syncthreads();
    int kcf = sh_kc;

    // fallback beyond row 512 (exact; not taken on this data)
    if (kcf < POST) {
        for (int w = lane; w < (PRE - TILE + 31) / 32; w += 64) fmask[w] = 0u;
        __syncthreads();
        for (int j = TILE + lane; j < PRE; j += 64) {
            float4 bj = g_boxes[(size_t)b * PRE + j];
            float  aj = g_area [(size_t)b * PRE + j];
            bool supd = false;
            for (int k = 0; k < kcf; ++k) {
                int i = (int)kept[k];
                float4 bi = g_boxes[(size_t)b * PRE + i];
                float  ai = g_area [(size_t)b * PRE + i];
                if (iou_gt(bi, ai, bj, aj)) { supd = true; break; }
            }
            if (supd) atomicOr(&fmask[(j - TILE) >> 5], 1u << ((j - TILE) & 31));
        }
        __syncthreads();
        int i = TILE;
        while (i < PRE && kcf < POST) {
            while (i < PRE && ((fmask[(i - TILE) >> 5] >> ((i - TILE) & 31)) & 1u)) ++i;
            if (i >= PRE) break;
            if (lane == 0) kept[kcf] = (uint32_t)i;
            ++kcf;
            if (kcf >= POST) break;
            float4 bi = g_boxes[(size_t)b * PRE + i];
            float  ai = g_area [(size_t)b * PRE + i];
            for (int j = i + 1 + lane; j < PRE; j += 64) {
                float4 bj = g_boxes[(size_t)b * PRE + j];
                float  aj = g_area [(size_t)b * PRE + j];
                if (iou_gt(bi, ai, bj, aj))
                    atomicOr(&fmask[(j - TILE) >> 5], 1u << ((j - TILE) & 31));
            }
            ++i;
            __syncthreads();
        }
    }
    __syncthreads();

    // write clipped output
    float4* ob = out + (size_t)b * POST;
    for (int r = lane; r < POST; r += 64) {
        float4 o = make_float4(0.f, 0.f, 0.f, 0.f);
        if (r < kcf) {
            float4 bx = g_boxes[(size_t)b * PRE + kept[r]];
            o.x = fminf(fmaxf(bx.x, 0.f), 1.f);
            o.y = fminf(fmaxf(bx.y, 0.f), 1.f);
            o.z = fminf(fmaxf(bx.z, 0.f), 1.f);
            o.w = fminf(fmaxf(bx.w, 0.f), 1.f);
        }
        ob[r] = o;
    }
    __syncthreads();

    } // rep
}

extern "C" void kernel_launch(void* const* d_in, const int* in_sizes, int n_in,
                              void* d_out, int out_size, void* d_ws, size_t ws_size,
                              hipStream_t stream) {
    const float4* deltas  = (const float4*)d_in[0];
    const float*  labels  = (const float*)d_in[1];
    const float4* anchors = (const float4*)d_in[2];
    const float4* score4  = (const float4*)labels;
    float4*       outp    = (float4*)d_out;
    const int N = in_sizes[2] / 4;      // 90000
    const int B = in_sizes[1] / N;      // 64

    char* ws = (char*)d_ws;
    const size_t SZ_BOXES  = (size_t)B * PRE * 16;
    const size_t SZ_PAIRS  = (size_t)B * SL * KBUF * 8;
    const size_t SZ_SUPMAT = (size_t)B * TILE * 16 * 4;
    const size_t SZ_SUPT   = (size_t)B * TILE * 8;
    const size_t SZ_AREA   = (size_t)B * PRE * 4;
    float4*   g_boxes  = (float4*)ws;
    u64*      g_pairs  = (u64*)(ws + SZ_BOXES);
    uint32_t* g_supmat = (uint32_t*)(ws + SZ_BOXES + SZ_PAIRS);
    uint32_t* g_supT   = (uint32_t*)(ws + SZ_BOXES + SZ_PAIRS + SZ_SUPMAT);
    float*    g_area   = (float*)(ws + SZ_BOXES + SZ_PAIRS + SZ_SUPMAT + SZ_SUPT);
    int*      g_scnt   = (int*)(ws + SZ_BOXES + SZ_PAIRS + SZ_SUPMAT + SZ_SUPT + SZ_AREA);

    k1_gather<<<B * SL, 256, 0, stream>>>(score4, g_pairs, g_scnt, N);
    k2_sort<<<B, 1024, 0, stream>>>(score4, g_pairs, g_scnt, deltas, anchors,
                                    g_boxes, g_area, g_supT, N);
    k4_supmat<<<B * 16, 256, 0, stream>>>(g_boxes, g_supmat);
    k5_sweep<<<B, 64, 0, stream>>>(g_supmat, (const u64*)g_supT,
                                   g_boxes, g_area, outp);
}

// Round 13
// 80.904 us; speedup vs baseline: 12.1832x; 12.1832x over previous
//
#include <hip/hip_runtime.h>
#include <stdint.h>

// RPN RoI proposal, 5-kernel pipeline, no pre-zeroed state. R13:
//  - decode un-fused from K2 (R12 instrumentation: fused decode at 64
//    blocks was concurrency-starved HBM gather, ~16us) -> K3 @ 256 blocks.
//  - K5 propagation loads made unconditional+masked (K is wave-uniform, so
//    conditional loads serialized ~300cyc each; unconditional pipelines).
//  K1 (B*16 x 256): threshold gather (bin>=CONS) into per-slice segments.
//     key = flip(f32)<<32 | bin<<20 | (0xFFFFF-idx): desc == lax.top_k.
//  K2 (B x 1024): 64-bin hist from keys; 1-wave suffix scan; counting
//     scatter; zero-barrier per-wave segment sorts -> g_sorted. Exact
//     hist-2048 fallback in-branch (never taken).
//  K3 (B*4 x 256): decode 512 ranks/block -> g_boxes, g_area.
//  K4 (B*16 x 256): suppression rows -> g_supmat[512][16]; s<8 blocks also
//     emit transposed diag col-words g_supT.
//  K5 (B x 64): chunked greedy sweep (ffs+ballot resolve; masked parallel
//     propagation reads); early-exit at 300; exact fallback beyond row 512
//     (never taken); write clipped [300,4] zero-padded.

#define PRE 2000
#define POST 300
#define TILE 512
#define IOU_THR 0.7f
#define EPSV 1e-8f
#define SORTN 2048
#define NBINS 2048
#define DESTCAP 4096
#define CANDCAP 512
#define CONS 1984
#define SL 16
#define KBUF 768

typedef unsigned long long u64;

__device__ __forceinline__ uint32_t flip_f32(uint32_t b) {
    return b ^ ((uint32_t)((int32_t)b >> 31) | 0x80000000u);
}

__device__ __forceinline__ int bin_of(float s) {
    int bn = (int)(s * 2048.0f);
    return min(max(bn, 0), NBINS - 1);
}

__device__ __forceinline__ u64 make_key(float s, int idx, int bn) {
    uint32_t ub = flip_f32(__float_as_uint(s));
    return ((u64)ub << 32) | ((uint32_t)bn << 20) |
           (uint32_t)(0xFFFFF - idx);
}

__device__ __forceinline__ bool iou_gt(const float4& bi, float ai,
                                       const float4& bj, float aj) {
    float yy1 = fmaxf(bi.x, bj.x);
    float xx1 = fmaxf(bi.y, bj.y);
    float yy2 = fminf(bi.z, bj.z);
    float xx2 = fminf(bi.w, bj.w);
    float inter = fmaxf(yy2 - yy1, 0.f) * fmaxf(xx2 - xx1, 0.f);
    float iou = inter / (ai + aj - inter + EPSV);
    return iou > IOU_THR;
}

__device__ __forceinline__ float area_of(const float4& bx) {
    // identical expression to K3's g_area computation -> bit-exact
    return fmaxf(bx.z - bx.x, 0.f) * fmaxf(bx.w - bx.y, 0.f);
}

__device__ __forceinline__ u64 cs_keep(u64 v, u64 pv, int i, int j, int k) {
    bool lower   = ((i & j) == 0);
    bool desc    = ((i & k) == 0);
    bool keepmax = (desc == lower);
    u64 mx = v > pv ? v : pv;
    u64 mn = v > pv ? pv : v;
    return keepmax ? mx : mn;
}

// ---------------- K1: pure threshold gather --------------------------------
__global__ __launch_bounds__(256) void k1_gather(
    const float4* __restrict__ score4,
    u64* __restrict__ g_pairs,           // [B*SL*KBUF]
    int* __restrict__ g_scnt,            // [B*SL] raw counts
    int N)
{
    const int blk = blockIdx.x;
    const int b   = blk / SL;
    const int s   = blk % SL;
    const int tid = threadIdx.x;
    const int F4PB = N >> 2;
    const int F4PS = (F4PB + SL - 1) / SL;

    __shared__ u64 keybuf[KBUF];
    __shared__ int kcnt;

    if (tid == 0) kcnt = 0;
    __syncthreads();

    const float4* src = score4 + (size_t)b * F4PB;
    const int n0 = s * F4PS, n1 = min(n0 + F4PS, F4PB);
    for (int n = n0 + tid; n < n1; n += 256) {
        float4 v = src[n];
        float sv[4] = {v.x, v.y, v.z, v.w};
#pragma unroll
        for (int c = 0; c < 4; ++c) {
            int bn = bin_of(sv[c]);
            if (bn >= CONS) {
                int q = atomicAdd(&kcnt, 1);
                if (q < KBUF) keybuf[q] = make_key(sv[c], 4 * n + c, bn);
            }
        }
    }
    __syncthreads();

    if (tid == 0) g_scnt[b * SL + s] = kcnt;   // raw (may exceed KBUF)
    int lc = min(kcnt, KBUF);
    u64* gp = g_pairs + ((size_t)b * SL + s) * KBUF;
    for (int i = tid; i < lc; i += 256) gp[i] = keybuf[i];
}

// ---------------- K2: superset sort -> g_sorted ----------------------------
__global__ __launch_bounds__(1024) void k2_sort(
    const float4* __restrict__ score4,
    const u64*  __restrict__ g_pairs,
    const int*  __restrict__ g_scnt,
    u64* __restrict__ g_sorted,
    int N)
{
    const int b    = blockIdx.x;
    const int tid  = threadIdx.x;
    const int lane = tid & 63;
    const int wv   = tid >> 6;

    __shared__ u64 dest[DESTCAP];
    __shared__ uint32_t hist2048[NBINS]; // fallback only
    __shared__ u64 cand[CANDCAP];
    __shared__ uint32_t hist64[64];
    __shared__ int segbase64[64];
    __shared__ uint32_t cur64[64];
    __shared__ int scnt_s[SL];
    __shared__ uint32_t wtot[16];
    __shared__ int sh_flag, sh_total, sh_bsel, sh_tprime, sh_cnt, sh_nc;
    __shared__ uint32_t sh_pivot;

    const int F4PB = N >> 2;

    if (tid < SL) scnt_s[tid] = g_scnt[b * SL + tid];
    if (tid < 64) { hist64[tid] = 0u; cur64[tid] = 0u; }
    if (tid == 0) { sh_flag = 0; sh_cnt = 0; sh_nc = 0; }
    __syncthreads();

    // pass 1: 64-bin hist from keys (wave wv handles slice wv)
    {
        int raw = scnt_s[wv];
        if (raw > KBUF) sh_flag = 1;     // benign same-value race
        int cs = min(raw, KBUF);
        const u64* gp = g_pairs + ((size_t)b * SL + wv) * KBUF;
        for (int i = lane; i < cs; i += 64) {
            int b64 = (int)((gp[i] >> 20) & 0xFFFu) - CONS;  // in [0,64)
            atomicAdd(&hist64[b64], 1u);
        }
    }
    __syncthreads();

    // 1-wave suffix scan of 64 bins
    if (wv == 0) {
        int h = (int)hist64[lane];
        int ssum = h;
#pragma unroll
        for (int off = 1; off < 64; off <<= 1) {
            int t = __shfl_down(ssum, off, 64);
            if (lane + off < 64) ssum += t;
        }
        segbase64[lane] = ssum - h;      // #keys in bins > lane
        if (lane == 0) sh_total = ssum;
        if (h > 128) sh_flag = 1;        // per-wave 2-reg sort cap
    }
    __syncthreads();
    const int total = sh_total;
    if (tid == 0 && (total < PRE || total > DESTCAP)) sh_flag = 1;
    __syncthreads();
    const bool flag = (sh_flag != 0);

    if (!flag) {
        // pass 2: counting-scatter to bin segments
        int cs = min(scnt_s[wv], KBUF);
        const u64* gp = g_pairs + ((size_t)b * SL + wv) * KBUF;
        for (int i = lane; i < cs; i += 64) {
            u64 key = gp[i];
            int b64 = (int)((key >> 20) & 0xFFFu) - CONS;
            int c = (int)atomicAdd(&cur64[b64], 1u);
            dest[segbase64[b64] + c] = key;
        }
        __syncthreads();
        // per-wave segment sorts (zero barriers)
        for (int sgi = wv; sgi < 64; sgi += 16) {
            int n = (int)cur64[sgi];
            if (n <= 0) continue;
            int base = segbase64[sgi];
            if (n <= 64) {
                u64 e = (lane < n) ? dest[base + lane] : 0ull;
#pragma unroll
                for (int k = 2; k <= 64; k <<= 1)
                    for (int j = k >> 1; j > 0; j >>= 1)
                        e = cs_keep(e, __shfl_xor(e, j, 64), lane, j, k);
                if (lane < n) dest[base + lane] = e;
            } else {                     // 65..128
                u64 e0 = (lane < n) ? dest[base + lane] : 0ull;
                u64 e1 = (lane + 64 < n) ? dest[base + lane + 64] : 0ull;
#pragma unroll
                for (int k = 2; k <= 128; k <<= 1) {
                    for (int j = k >> 1; j > 0; j >>= 1) {
                        if (j == 64) {
                            u64 a = e0, c = e1;
                            e0 = cs_keep(a, c, lane, 64, k);
                            e1 = cs_keep(c, a, lane + 64, 64, k);
                        } else {
                            e0 = cs_keep(e0, __shfl_xor(e0, j, 64), lane, j, k);
                            e1 = cs_keep(e1, __shfl_xor(e1, j, 64), lane + 64, j, k);
                        }
                    }
                }
                if (lane < n) dest[base + lane] = e0;
                if (lane + 64 < n) dest[base + lane + 64] = e1;
            }
        }
        __syncthreads();
        // store top-2048 sorted keys
        g_sorted[(size_t)b * SORTN + tid]        = dest[tid];
        g_sorted[(size_t)b * SORTN + tid + 1024] = dest[tid + 1024];
    } else {
        // exact fallback: hist-based top-2000 (never taken on this data)
        hist2048[tid] = 0u; hist2048[tid + 1024] = 0u;
        if (tid == 0) { sh_cnt = 0; sh_nc = 0; }
        __syncthreads();
        const float4* src = score4 + (size_t)b * F4PB;
        for (int n = tid; n < F4PB; n += 1024) {
            float4 v = src[n];
            atomicAdd(&hist2048[bin_of(v.x)], 1u);
            atomicAdd(&hist2048[bin_of(v.y)], 1u);
            atomicAdd(&hist2048[bin_of(v.z)], 1u);
            atomicAdd(&hist2048[bin_of(v.w)], 1u);
        }
        __syncthreads();
        {   // 16-wave suffix scan
            const int i0 = wv * 128 + lane;
            const int i1 = i0 + 64;
            int h0 = (int)hist2048[i0];
            int h1 = (int)hist2048[i1];
            int s0 = h0, s1 = h1;
#pragma unroll
            for (int off = 1; off < 64; off <<= 1) {
                int t0 = __shfl_down(s0, off, 64);
                int t1 = __shfl_down(s1, off, 64);
                if (lane + off < 64) { s0 += t0; s1 += t1; }
            }
            int sum_h1 = __shfl(s1, 0, 64);
            if (lane == 0) wtot[wv] = (uint32_t)(__shfl(s0, 0, 64) + sum_h1);
            __syncthreads();
            int offtot = 0;
            for (int w2 = wv + 1; w2 < 16; ++w2) offtot += (int)wtot[w2];
            int S0 = s0 + sum_h1 + offtot;
            int S1 = s1 + offtot;
            if (S0 >= PRE && S0 - h0 < PRE) { sh_bsel = i0; sh_tprime = PRE - (S0 - h0); }
            if (S1 >= PRE && S1 - h1 < PRE) { sh_bsel = i1; sh_tprime = PRE - (S1 - h1); }
        }
        __syncthreads();
        const int bsel   = sh_bsel;
        const int tprime = sh_tprime;
        for (int n = tid; n < F4PB; n += 1024) {
            float4 v = src[n];
            float sv[4] = {v.x, v.y, v.z, v.w};
#pragma unroll
            for (int c = 0; c < 4; ++c) {
                int bn = bin_of(sv[c]);
                if (bn >= bsel) {
                    u64 key = make_key(sv[c], 4 * n + c, bn);
                    if (bn > bsel) {
                        int q = atomicAdd(&sh_cnt, 1);
                        if (q < SORTN) dest[q] = key;
                    } else {
                        int t = atomicAdd(&sh_nc, 1);
                        if (t < CANDCAP) cand[t] = key;
                    }
                }
            }
        }
        __syncthreads();
        const int nc = min(sh_nc, CANDCAP);
        for (int i = tid; i < nc; i += 1024) {
            uint32_t vi = (uint32_t)(cand[i] >> 32);
            int g = 0, e = 0;
            for (int j = 0; j < nc; ++j) {
                uint32_t vj = (uint32_t)(cand[j] >> 32);
                g += (vj > vi);
                e += (vj == vi);
            }
            if (g < tprime && g + e >= tprime) sh_pivot = vi;
        }
        __syncthreads();
        const uint32_t pivot = sh_pivot;
        for (int i = tid; i < nc; i += 1024) {
            uint32_t vi = (uint32_t)(cand[i] >> 32);
            if (vi >= pivot) {
                int q = atomicAdd(&sh_cnt, 1);
                if (q < SORTN) dest[q] = cand[i];
            }
        }
        __syncthreads();
        const int tt = min(sh_cnt, SORTN);
        for (int q = tt + tid; q < SORTN; q += 1024) dest[q] = 0ull;
        __syncthreads();
        {   // full register bitonic over dest[0..2048)
            const int i0 = wv * 128 + lane;
            const int i1 = i0 + 64;
            u64 e0 = dest[i0];
            u64 e1 = dest[i1];
            for (int k = 2; k <= SORTN; k <<= 1) {
                for (int j = k >> 1; j > 0; j >>= 1) {
                    if (j >= 128) {
                        dest[i0] = e0;
                        dest[i1] = e1;
                        __syncthreads();
                        u64 p0 = dest[i0 ^ j];
                        u64 p1 = dest[i1 ^ j];
                        __syncthreads();
                        e0 = cs_keep(e0, p0, i0, j, k);
                        e1 = cs_keep(e1, p1, i1, j, k);
                    } else if (j == 64) {
                        u64 a = e0, c = e1;
                        e0 = cs_keep(a, c, i0, 64, k);
                        e1 = cs_keep(c, a, i1, 64, k);
                    } else {
                        e0 = cs_keep(e0, __shfl_xor(e0, j, 64), i0, j, k);
                        e1 = cs_keep(e1, __shfl_xor(e1, j, 64), i1, j, k);
                    }
                }
            }
            g_sorted[(size_t)b * SORTN + i0] = e0;
            g_sorted[(size_t)b * SORTN + i1] = e1;
        }
    }
}

// ---------------- K3: decode sorted top-2000 (high concurrency) ------------
__global__ __launch_bounds__(256) void k3_decode(
    const float4* __restrict__ deltas,
    const float4* __restrict__ anchors,
    const u64*  __restrict__ g_sorted,
    float4* __restrict__ g_boxes,
    float*  __restrict__ g_area,
    int N)
{
    const int b   = blockIdx.x >> 2;
    const int s   = blockIdx.x & 3;
    const int tid = threadIdx.x;
    const int r0 = s * 512, r1 = min(r0 + 512, PRE);

    const float4* dl = deltas + (size_t)b * N;
    for (int r = r0 + tid; r < r1; r += 256) {
        u64 key = g_sorted[(size_t)b * SORTN + r];
        uint32_t idx = 0xFFFFFu - (uint32_t)(key & 0xFFFFFull);
        float4 bx = make_float4(0.f, 0.f, 0.f, 0.f);
        float  ar = 0.f;
        if (idx < (uint32_t)N) {
            float4 d  = dl[idx];
            float4 an = anchors[idx];
            float ah  = an.z - an.x;
            float aw  = an.w - an.y;
            float acy = an.x + 0.5f * ah;
            float acx = an.y + 0.5f * aw;
            float h   = expf(d.z) * ah;
            float w   = expf(d.w) * aw;
            float cy  = d.x * ah + acy;
            float cx  = d.y * aw + acx;
            float y1  = cy - 0.5f * h;
            float x1  = cx - 0.5f * w;
            bx = make_float4(y1, x1, y1 + h, x1 + w);
            ar = fmaxf(bx.z - bx.x, 0.f) * fmaxf(bx.w - bx.y, 0.f);
        }
        g_boxes[(size_t)b * PRE + r] = bx;
        g_area [(size_t)b * PRE + r] = ar;
    }
}

// ---------------- K4: suppression matrix + supT (high-occupancy) -----------
__global__ __launch_bounds__(256) void k4_supmat(
    const float4* __restrict__ g_boxes,
    uint32_t* __restrict__ g_supmat,     // [B*512*16] row-major
    uint32_t* __restrict__ g_supT)       // [B*512*2]  diag col-words
{
    const int b   = blockIdx.x >> 4;
    const int s   = blockIdx.x & 15;
    const int tid = threadIdx.x;

    __shared__ float4 box[TILE];
    for (int i = tid; i < TILE; i += 256)
        box[i] = g_boxes[(size_t)b * PRE + i];
    __syncthreads();

    const int rbase = s * 32;
#pragma unroll
    for (int k = 0; k < 2; ++k) {
        int idx = tid + k * 256;
        int row = rbase + (idx & 31);
        int w   = idx >> 5;
        int jbase = w << 5;
        float4 bi = box[row];
        float  ai = area_of(bi);
        uint32_t bits = 0u;
        if (jbase + 31 > row) {
#pragma unroll
            for (int c = 0; c < 32; ++c) {
                int j = jbase + c;
                float4 bj = box[j];
                float  aj = area_of(bj);
                bool gt = (j > row) & iou_gt(bi, ai, bj, aj);  // branchless
                bits |= ((uint32_t)gt) << c;
            }
        }
        g_supmat[((size_t)b * TILE + row) * 16 + w] = bits;
    }

    // transposed diagonal blocks: blocks s<8 emit chunk q=s (64 cols x 2)
    if (s < 8 && tid < 128) {
        int q  = s;
        int j  = tid >> 1;
        int w2 = tid & 1;
        int C  = q * 64 + j;
        float4 bc = box[C];
        float  ac = area_of(bc);
        uint32_t bits = 0u;
#pragma unroll
        for (int c = 0; c < 32; ++c) {
            int R = q * 64 + w2 * 32 + c;
            float4 br = box[R];
            float  ar = area_of(br);
            bool gt = (R < C) & iou_gt(br, ar, bc, ac);
            bits |= ((uint32_t)gt) << c;
        }
        g_supT[((size_t)b * TILE + C) * 2 + w2] = bits;
    }
}

// ---------------- K5: ballot-resolve chunked greedy sweep ------------------
__global__ __launch_bounds__(64) void k5_sweep(
    const uint32_t* __restrict__ g_supmat,
    const u64*    __restrict__ g_supT64,   // [B*512] diag col-words
    const float4* __restrict__ g_boxes,
    const float*  __restrict__ g_area,
    float4* __restrict__ out)
{
    const int b    = blockIdx.x;
    const int lane = threadIdx.x;

    __shared__ uint32_t kept[POST];
    __shared__ u64 sh_keepbits[TILE / 64];
    __shared__ uint32_t fmask[(PRE - TILE + 31) / 32];
    __shared__ int sh_kc;

    const u64* tdbase = g_supT64 + (size_t)b * TILE;

    uint32_t removedw = 0u;              // lanes 0..15: removed word
    int kc = 0, nq = 0;
    u64 cw_cur = tdbase[lane];
    for (int q = 0; q < TILE / 64; ++q) {
        u64 cw_next = (q < TILE / 64 - 1) ? tdbase[(q + 1) * 64 + lane] : 0ull;
        const int cbase = q << 6;
        uint32_t rlo = (uint32_t)__builtin_amdgcn_readlane((int)removedw, 2 * q);
        uint32_t rhi = (uint32_t)__builtin_amdgcn_readlane((int)removedw, 2 * q + 1);
        u64 avail = ~(((u64)rhi << 32) | rlo);
        u64 K = 0ull;
        while (avail) {                  // ballot-based greedy resolve
            int i = __ffsll((long long)avail) - 1;
            K |= (1ull << i);
            u64 supp = __ballot(((cw_cur >> i) & 1ull) != 0ull);
            avail &= ~(supp | (1ull << i));
        }
        if (lane == 0) sh_keepbits[q] = K;
        kc += __popcll(K);
        nq = q + 1;
        if (kc >= POST) break;
        // propagation: UNCONDITIONAL loads (pipeline) + mask-select OR.
        // K is wave-uniform; conditional loads serialized ~300cyc each.
        if (K) {
            const int w = lane & 15;
            const int g = lane >> 4;
            const uint32_t* gs =
                g_supmat + ((size_t)b * TILE + cbase + g * 16) * 16 + w;
            uint32_t acc = 0u;
#pragma unroll
            for (int r = 0; r < 16; ++r) {
                uint32_t v = gs[(size_t)r * 16];                // always load
                uint32_t m = (uint32_t)0 - (uint32_t)((K >> (g * 16 + r)) & 1ull);
                acc |= (v & m);
            }
            acc |= (uint32_t)__shfl_xor((int)acc, 16, 64);
            acc |= (uint32_t)__shfl_xor((int)acc, 32, 64);
            if (lane < 16) removedw |= acc;
        }
        cw_cur = cw_next;
    }
    {
        int base = 0;
        for (int q = 0; q < nq; ++q) {
            u64 kbq = sh_keepbits[q];
            int pos = base + __popcll(kbq & ((1ull << lane) - 1));
            if (((kbq >> lane) & 1ull) && pos < POST)
                kept[pos] = (uint32_t)(q * 64 + lane);
            base += __popcll(kbq);
        }
        if (lane == 0) sh_kc = min(kc, POST);
    }
    __syncthreads();
    int kcf = sh_kc;

    // fallback beyond row 512 (exact; not taken on this data)
    if (kcf < POST) {
        for (int w = lane; w < (PRE - TILE + 31) / 32; w += 64) fmask[w] = 0u;
        __syncthreads();
        for (int j = TILE + lane; j < PRE; j += 64) {
            float4 bj = g_boxes[(size_t)b * PRE + j];
            float  aj = g_area [(size_t)b * PRE + j];
            bool supd = false;
            for (int k = 0; k < kcf; ++k) {
                int i = (int)kept[k];
                float4 bi = g_boxes[(size_t)b * PRE + i];
                float  ai = g_area [(size_t)b * PRE + i];
                if (iou_gt(bi, ai, bj, aj)) { supd = true; break; }
            }
            if (supd) atomicOr(&fmask[(j - TILE) >> 5], 1u << ((j - TILE) & 31));
        }
        __syncthreads();
        int i = TILE;
        while (i < PRE && kcf < POST) {
            while (i < PRE && ((fmask[(i - TILE) >> 5] >> ((i - TILE) & 31)) & 1u)) ++i;
            if (i >= PRE) break;
            if (lane == 0) kept[kcf] = (uint32_t)i;
            ++kcf;
            if (kcf >= POST) break;
            float4 bi = g_boxes[(size_t)b * PRE + i];
            float  ai = g_area [(size_t)b * PRE + i];
            for (int j = i + 1 + lane; j < PRE; j += 64) {
                float4 bj = g_boxes[(size_t)b * PRE + j];
                float  aj = g_area [(size_t)b * PRE + j];
                if (iou_gt(bi, ai, bj, aj))
                    atomicOr(&fmask[(j - TILE) >> 5], 1u << ((j - TILE) & 31));
            }
            ++i;
            __syncthreads();
        }
    }
    __syncthreads();

    // write clipped output
    float4* ob = out + (size_t)b * POST;
    for (int r = lane; r < POST; r += 64) {
        float4 o = make_float4(0.f, 0.f, 0.f, 0.f);
        if (r < kcf) {
            float4 bx = g_boxes[(size_t)b * PRE + kept[r]];
            o.x = fminf(fmaxf(bx.x, 0.f), 1.f);
            o.y = fminf(fmaxf(bx.y, 0.f), 1.f);
            o.z = fminf(fmaxf(bx.z, 0.f), 1.f);
            o.w = fminf(fmaxf(bx.w, 0.f), 1.f);
        }
        ob[r] = o;
    }
}

extern "C" void kernel_launch(void* const* d_in, const int* in_sizes, int n_in,
                              void* d_out, int out_size, void* d_ws, size_t ws_size,
                              hipStream_t stream) {
    const float4* deltas  = (const float4*)d_in[0];
    const float*  labels  = (const float*)d_in[1];
    const float4* anchors = (const float4*)d_in[2];
    const float4* score4  = (const float4*)labels;
    float4*       outp    = (float4*)d_out;
    const int N = in_sizes[2] / 4;      // 90000
    const int B = in_sizes[1] / N;      // 64

    // workspace (16B-aligned chunks), no zero-init required anywhere:
    // boxes | pairs | sorted | supmat | supT | area | scnt
    char* ws = (char*)d_ws;
    const size_t SZ_BOXES  = (size_t)B * PRE * 16;
    const size_t SZ_PAIRS  = (size_t)B * SL * KBUF * 8;
    const size_t SZ_SORTED = (size_t)B * SORTN * 8;
    const size_t SZ_SUPMAT = (size_t)B * TILE * 16 * 4;
    const size_t SZ_SUPT   = (size_t)B * TILE * 8;
    const size_t SZ_AREA   = (size_t)B * PRE * 4;
    float4*   g_boxes  = (float4*)ws;
    u64*      g_pairs  = (u64*)(ws + SZ_BOXES);
    u64*      g_sorted = (u64*)(ws + SZ_BOXES + SZ_PAIRS);
    uint32_t* g_supmat = (uint32_t*)(ws + SZ_BOXES + SZ_PAIRS + SZ_SORTED);
    uint32_t* g_supT   = (uint32_t*)(ws + SZ_BOXES + SZ_PAIRS + SZ_SORTED + SZ_SUPMAT);
    float*    g_area   = (float*)(ws + SZ_BOXES + SZ_PAIRS + SZ_SORTED + SZ_SUPMAT + SZ_SUPT);
    int*      g_scnt   = (int*)(ws + SZ_BOXES + SZ_PAIRS + SZ_SORTED + SZ_SUPMAT + SZ_SUPT + SZ_AREA);

    k1_gather<<<B * SL, 256, 0, stream>>>(score4, g_pairs, g_scnt, N);
    k2_sort<<<B, 1024, 0, stream>>>(score4, g_pairs, g_scnt, g_sorted, N);
    k3_decode<<<B * 4, 256, 0, stream>>>(deltas, anchors, g_sorted,
                                         g_boxes, g_area, N);
    k4_supmat<<<B * 16, 256, 0, stream>>>(g_boxes, g_supmat, g_supT);
    k5_sweep<<<B, 64, 0, stream>>>(g_supmat, (const u64*)g_supT,
                                   g_boxes, g_area, outp);
}

// Round 14
// 75.684 us; speedup vs baseline: 13.0234x; 1.0690x over previous
//
#include <hip/hip_runtime.h>
#include <stdint.h>

// RPN RoI proposal, 4-kernel pipeline, no pre-zeroed state. R14:
//  - K1 pre-bins keys per slice (64-bin LDS hist + bin-grouped writeout +
//    hist table) so K2 needs ONE key pass with arithmetic destinations
//    (no atomics, no hist pass).
//  - K3 merged into K4: each supmat block decodes its 512 boxes from
//    g_sorted (redundant, latency-hidden at 4 blocks/CU); s==0 persists
//    g_boxes[0..512). K5 fallback (never taken) decodes 0..2000 itself.
//  K1 (B*16 x 256): threshold gather (bin>=CONS) -> bin-grouped per-slice
//     segments + per-slice 64-bin hist. key = flip(f32)<<32 | bin<<20 |
//     (0xFFFFF-idx): u64 desc == lax.top_k order (incl. tie-break).
//  K2 (B x 1024): scatter via scanned hist tables; zero-barrier per-wave
//     segment bitonic sorts -> g_sorted. Exact hist-2048 fallback in-branch
//     (total<2000 / >4096 / slice>KBUF / bin>128; never taken).
//  K4 (B*16 x 256): decode 512 ranks into LDS; 32 rows x 16 words/block ->
//     g_supmat; s<8 emit transposed diag col-words g_supT; s==0 writes
//     g_boxes[0..512).
//  K5 (B x 64): chunked greedy sweep (ffs+ballot resolve; masked pipelined
//     propagation); early-exit at 300; exact fallback (decodes 2000 boxes
//     into LDS; never taken); write clipped [300,4] zero-padded.

#define PRE 2000
#define POST 300
#define TILE 512
#define IOU_THR 0.7f
#define EPSV 1e-8f
#define SORTN 2048
#define NBINS 2048
#define DESTCAP 4096
#define CANDCAP 512
#define CONS 1984
#define SL 16
#define KBUF 768

typedef unsigned long long u64;

__device__ __forceinline__ uint32_t flip_f32(uint32_t b) {
    return b ^ ((uint32_t)((int32_t)b >> 31) | 0x80000000u);
}

__device__ __forceinline__ int bin_of(float s) {
    int bn = (int)(s * 2048.0f);
    return min(max(bn, 0), NBINS - 1);
}

__device__ __forceinline__ u64 make_key(float s, int idx, int bn) {
    uint32_t ub = flip_f32(__float_as_uint(s));
    return ((u64)ub << 32) | ((uint32_t)bn << 20) |
           (uint32_t)(0xFFFFF - idx);
}

__device__ __forceinline__ bool iou_gt(const float4& bi, float ai,
                                       const float4& bj, float aj) {
    float yy1 = fmaxf(bi.x, bj.x);
    float xx1 = fmaxf(bi.y, bj.y);
    float yy2 = fminf(bi.z, bj.z);
    float xx2 = fminf(bi.w, bj.w);
    float inter = fmaxf(yy2 - yy1, 0.f) * fmaxf(xx2 - xx1, 0.f);
    float iou = inter / (ai + aj - inter + EPSV);
    return iou > IOU_THR;
}

__device__ __forceinline__ float area_of(const float4& bx) {
    return fmaxf(bx.z - bx.x, 0.f) * fmaxf(bx.w - bx.y, 0.f);
}

// decode one key -> box (identical expression everywhere -> bit-exact)
__device__ __forceinline__ float4 decode_key(u64 key, const float4* dl,
                                             const float4* anchors, int N) {
    uint32_t idx = 0xFFFFFu - (uint32_t)(key & 0xFFFFFull);
    if (idx >= (uint32_t)N) return make_float4(0.f, 0.f, 0.f, 0.f);
    float4 d  = dl[idx];
    float4 an = anchors[idx];
    float ah  = an.z - an.x;
    float aw  = an.w - an.y;
    float acy = an.x + 0.5f * ah;
    float acx = an.y + 0.5f * aw;
    float h   = expf(d.z) * ah;
    float w   = expf(d.w) * aw;
    float cy  = d.x * ah + acy;
    float cx  = d.y * aw + acx;
    float y1  = cy - 0.5f * h;
    float x1  = cx - 0.5f * w;
    return make_float4(y1, x1, y1 + h, x1 + w);
}

__device__ __forceinline__ u64 cs_keep(u64 v, u64 pv, int i, int j, int k) {
    bool lower   = ((i & j) == 0);
    bool desc    = ((i & k) == 0);
    bool keepmax = (desc == lower);
    u64 mx = v > pv ? v : pv;
    u64 mn = v > pv ? pv : v;
    return keepmax ? mx : mn;
}

// ---------------- K1: threshold gather + per-slice binning -----------------
__global__ __launch_bounds__(256) void k1_gather(
    const float4* __restrict__ score4,
    u64* __restrict__ g_pairs,           // [B*SL*KBUF] bin-grouped per slice
    int* __restrict__ g_scnt,            // [B*SL] raw counts
    uint32_t* __restrict__ g_shist,      // [B*SL*64] per-slice bin hist
    int N)
{
    const int blk = blockIdx.x;
    const int b   = blk / SL;
    const int s   = blk % SL;
    const int tid = threadIdx.x;
    const int lane = tid & 63;
    const int F4PB = N >> 2;
    const int F4PS = (F4PB + SL - 1) / SL;

    __shared__ u64 keybuf[KBUF];
    __shared__ u64 binbuf[KBUF];
    __shared__ uint32_t hist64[64];
    __shared__ int base64[64];
    __shared__ uint32_t cur64[64];
    __shared__ int kcnt;

    if (tid < 64) { hist64[tid] = 0u; cur64[tid] = 0u; }
    if (tid == 0) kcnt = 0;
    __syncthreads();

    const float4* src = score4 + (size_t)b * F4PB;
    const int n0 = s * F4PS, n1 = min(n0 + F4PS, F4PB);
    for (int n = n0 + tid; n < n1; n += 256) {
        float4 v = src[n];
        float sv[4] = {v.x, v.y, v.z, v.w};
#pragma unroll
        for (int c = 0; c < 4; ++c) {
            int bn = bin_of(sv[c]);
            if (bn >= CONS) {
                int q = atomicAdd(&kcnt, 1);
                if (q < KBUF) keybuf[q] = make_key(sv[c], 4 * n + c, bn);
            }
        }
    }
    __syncthreads();

    const int raw = kcnt;
    const int lc  = min(raw, KBUF);

    for (int i = tid; i < lc; i += 256) {
        int b64 = (int)((keybuf[i] >> 20) & 0xFFFu) - CONS;  // in [0,64)
        atomicAdd(&hist64[b64], 1u);
    }
    __syncthreads();

    if (tid < 64) {
        int h = (int)hist64[lane];
        int ssum = h;
#pragma unroll
        for (int off = 1; off < 64; off <<= 1) {
            int t = __shfl_down(ssum, off, 64);
            if (lane + off < 64) ssum += t;
        }
        base64[lane] = ssum - h;         // #keys in bins > lane (desc order)
    }
    __syncthreads();

    for (int i = tid; i < lc; i += 256) {
        u64 key = keybuf[i];
        int b64 = (int)((key >> 20) & 0xFFFu) - CONS;
        int p = (int)atomicAdd(&cur64[b64], 1u);
        binbuf[base64[b64] + p] = key;   // within-bin order arbitrary; sorted later
    }
    __syncthreads();

    if (tid == 0) g_scnt[b * SL + s] = raw;
    if (tid < 64) g_shist[((size_t)b * SL + s) * 64 + tid] = hist64[tid];
    u64* gp = g_pairs + ((size_t)b * SL + s) * KBUF;
    for (int i = tid; i < lc; i += 256) gp[i] = binbuf[i];
}

// ---------------- K2: arithmetic scatter + segmented sort ------------------
__global__ __launch_bounds__(1024) void k2_sort(
    const float4* __restrict__ score4,
    const u64*  __restrict__ g_pairs,
    const int*  __restrict__ g_scnt,
    const uint32_t* __restrict__ g_shist,
    u64* __restrict__ g_sorted,
    int N)
{
    const int b    = blockIdx.x;
    const int tid  = threadIdx.x;
    const int lane = tid & 63;
    const int wv   = tid >> 6;

    __shared__ u64 dest[DESTCAP];
    __shared__ uint32_t hist2048[NBINS]; // fallback only
    __shared__ u64 cand[CANDCAP];        // fallback only
    __shared__ uint32_t shist[SL][64];
    __shared__ int srcb[SL][64];
    __shared__ int sbase[SL][64];
    __shared__ int tot64[64];
    __shared__ int segbase64[64];
    __shared__ uint32_t wtot[16];
    __shared__ int sh_flag, sh_total, sh_bsel, sh_tprime, sh_cnt, sh_nc;
    __shared__ uint32_t sh_pivot;

    const int F4PB = N >> 2;

    shist[tid >> 6][tid & 63] = g_shist[(size_t)b * SL * 64 + tid];
    if (tid == 0) {
        int f = 0;
#pragma unroll
        for (int s = 0; s < SL; ++s)
            if (g_scnt[b * SL + s] > KBUF) f = 1;
        sh_flag = f;
    }
    __syncthreads();

    if (tid < 64) {
        int acc = 0;
#pragma unroll
        for (int s = 0; s < SL; ++s) acc += (int)shist[s][tid];
        tot64[tid] = acc;
        if (acc > 128) sh_flag = 1;      // per-wave 2-reg sort cap
    }
    {
        int h = (int)shist[wv][lane];
        int ssum = h;
#pragma unroll
        for (int off = 1; off < 64; off <<= 1) {
            int t = __shfl_down(ssum, off, 64);
            if (lane + off < 64) ssum += t;
        }
        srcb[wv][lane] = ssum - h;       // within-slice base (desc bins)
    }
    __syncthreads();

    if (tid < 64) {
        int t0 = tot64[lane];
        int ssum = t0;
#pragma unroll
        for (int off = 1; off < 64; off <<= 1) {
            int t = __shfl_down(ssum, off, 64);
            if (lane + off < 64) ssum += t;
        }
        segbase64[lane] = ssum - t0;
        if (lane == 0) sh_total = ssum;
    }
    __syncthreads();
    const int total = sh_total;
    if (tid == 0 && (total < PRE || total > DESTCAP)) sh_flag = 1;
    {
        int s   = tid >> 6;
        int b64 = tid & 63;
        int pre = 0;
        for (int s2 = 0; s2 < s; ++s2) pre += (int)shist[s2][b64];
        sbase[s][b64] = segbase64[b64] + pre;
    }
    __syncthreads();
    const bool flag = (sh_flag != 0);

    if (!flag) {
        const int cs = min(g_scnt[b * SL + wv], KBUF);
        const u64* gp = g_pairs + ((size_t)b * SL + wv) * KBUF;
        for (int i = lane; i < cs; i += 64) {
            u64 key = gp[i];
            int b64 = (int)((key >> 20) & 0xFFFu) - CONS;
            dest[sbase[wv][b64] + (i - srcb[wv][b64])] = key;
        }
        __syncthreads();
        for (int sgi = wv; sgi < 64; sgi += 16) {
            int n = tot64[sgi];
            if (n <= 0) continue;
            int base = segbase64[sgi];
            if (n <= 64) {
                u64 e = (lane < n) ? dest[base + lane] : 0ull;
#pragma unroll
                for (int k = 2; k <= 64; k <<= 1)
                    for (int j = k >> 1; j > 0; j >>= 1)
                        e = cs_keep(e, __shfl_xor(e, j, 64), lane, j, k);
                if (lane < n) dest[base + lane] = e;
            } else {                     // 65..128
                u64 e0 = (lane < n) ? dest[base + lane] : 0ull;
                u64 e1 = (lane + 64 < n) ? dest[base + lane + 64] : 0ull;
#pragma unroll
                for (int k = 2; k <= 128; k <<= 1) {
                    for (int j = k >> 1; j > 0; j >>= 1) {
                        if (j == 64) {
                            u64 a = e0, c = e1;
                            e0 = cs_keep(a, c, lane, 64, k);
                            e1 = cs_keep(c, a, lane + 64, 64, k);
                        } else {
                            e0 = cs_keep(e0, __shfl_xor(e0, j, 64), lane, j, k);
                            e1 = cs_keep(e1, __shfl_xor(e1, j, 64), lane + 64, j, k);
                        }
                    }
                }
                if (lane < n) dest[base + lane] = e0;
                if (lane + 64 < n) dest[base + lane + 64] = e1;
            }
        }
        __syncthreads();
        g_sorted[(size_t)b * SORTN + tid]        = dest[tid];
        g_sorted[(size_t)b * SORTN + tid + 1024] = dest[tid + 1024];
    } else {
        // exact fallback: hist-based top-2000 (never taken on this data)
        hist2048[tid] = 0u; hist2048[tid + 1024] = 0u;
        if (tid == 0) { sh_cnt = 0; sh_nc = 0; }
        __syncthreads();
        const float4* src = score4 + (size_t)b * F4PB;
        for (int n = tid; n < F4PB; n += 1024) {
            float4 v = src[n];
            atomicAdd(&hist2048[bin_of(v.x)], 1u);
            atomicAdd(&hist2048[bin_of(v.y)], 1u);
            atomicAdd(&hist2048[bin_of(v.z)], 1u);
            atomicAdd(&hist2048[bin_of(v.w)], 1u);
        }
        __syncthreads();
        {
            const int i0 = wv * 128 + lane;
            const int i1 = i0 + 64;
            int h0 = (int)hist2048[i0];
            int h1 = (int)hist2048[i1];
            int s0 = h0, s1 = h1;
#pragma unroll
            for (int off = 1; off < 64; off <<= 1) {
                int t0 = __shfl_down(s0, off, 64);
                int t1 = __shfl_down(s1, off, 64);
                if (lane + off < 64) { s0 += t0; s1 += t1; }
            }
            int sum_h1 = __shfl(s1, 0, 64);
            if (lane == 0) wtot[wv] = (uint32_t)(__shfl(s0, 0, 64) + sum_h1);
            __syncthreads();
            int offtot = 0;
            for (int w2 = wv + 1; w2 < 16; ++w2) offtot += (int)wtot[w2];
            int S0 = s0 + sum_h1 + offtot;
            int S1 = s1 + offtot;
            if (S0 >= PRE && S0 - h0 < PRE) { sh_bsel = i0; sh_tprime = PRE - (S0 - h0); }
            if (S1 >= PRE && S1 - h1 < PRE) { sh_bsel = i1; sh_tprime = PRE - (S1 - h1); }
        }
        __syncthreads();
        const int bsel   = sh_bsel;
        const int tprime = sh_tprime;
        for (int n = tid; n < F4PB; n += 1024) {
            float4 v = src[n];
            float sv[4] = {v.x, v.y, v.z, v.w};
#pragma unroll
            for (int c = 0; c < 4; ++c) {
                int bn = bin_of(sv[c]);
                if (bn >= bsel) {
                    u64 key = make_key(sv[c], 4 * n + c, bn);
                    if (bn > bsel) {
                        int q = atomicAdd(&sh_cnt, 1);
                        if (q < SORTN) dest[q] = key;
                    } else {
                        int t = atomicAdd(&sh_nc, 1);
                        if (t < CANDCAP) cand[t] = key;
                    }
                }
            }
        }
        __syncthreads();
        const int nc = min(sh_nc, CANDCAP);
        for (int i = tid; i < nc; i += 1024) {
            uint32_t vi = (uint32_t)(cand[i] >> 32);
            int g = 0, e = 0;
            for (int j = 0; j < nc; ++j) {
                uint32_t vj = (uint32_t)(cand[j] >> 32);
                g += (vj > vi);
                e += (vj == vi);
            }
            if (g < tprime && g + e >= tprime) sh_pivot = vi;
        }
        __syncthreads();
        const uint32_t pivot = sh_pivot;
        for (int i = tid; i < nc; i += 1024) {
            uint32_t vi = (uint32_t)(cand[i] >> 32);
            if (vi >= pivot) {
                int q = atomicAdd(&sh_cnt, 1);
                if (q < SORTN) dest[q] = cand[i];
            }
        }
        __syncthreads();
        const int tt = min(sh_cnt, SORTN);
        for (int q = tt + tid; q < SORTN; q += 1024) dest[q] = 0ull;
        __syncthreads();
        {
            const int i0 = wv * 128 + lane;
            const int i1 = i0 + 64;
            u64 e0 = dest[i0];
            u64 e1 = dest[i1];
            for (int k = 2; k <= SORTN; k <<= 1) {
                for (int j = k >> 1; j > 0; j >>= 1) {
                    if (j >= 128) {
                        dest[i0] = e0;
                        dest[i1] = e1;
                        __syncthreads();
                        u64 p0 = dest[i0 ^ j];
                        u64 p1 = dest[i1 ^ j];
                        __syncthreads();
                        e0 = cs_keep(e0, p0, i0, j, k);
                        e1 = cs_keep(e1, p1, i1, j, k);
                    } else if (j == 64) {
                        u64 a = e0, c = e1;
                        e0 = cs_keep(a, c, i0, 64, k);
                        e1 = cs_keep(c, a, i1, 64, k);
                    } else {
                        e0 = cs_keep(e0, __shfl_xor(e0, j, 64), i0, j, k);
                        e1 = cs_keep(e1, __shfl_xor(e1, j, 64), i1, j, k);
                    }
                }
            }
            g_sorted[(size_t)b * SORTN + i0] = e0;
            g_sorted[(size_t)b * SORTN + i1] = e1;
        }
    }
}

// ---------------- K4: fused decode + suppression matrix + supT -------------
__global__ __launch_bounds__(256) void k4_supmat(
    const float4* __restrict__ deltas,
    const float4* __restrict__ anchors,
    const u64*  __restrict__ g_sorted,
    float4* __restrict__ g_boxes,        // [B*512]
    uint32_t* __restrict__ g_supmat,     // [B*512*16] row-major
    uint32_t* __restrict__ g_supT,       // [B*512*2]  diag col-words
    int N)
{
    const int b   = blockIdx.x >> 4;
    const int s   = blockIdx.x & 15;
    const int tid = threadIdx.x;

    __shared__ float4 box[TILE];

    const float4* dl = deltas + (size_t)b * N;
#pragma unroll
    for (int k = 0; k < 2; ++k) {
        int r = tid + k * 256;
        box[r] = decode_key(g_sorted[(size_t)b * SORTN + r], dl, anchors, N);
    }
    __syncthreads();

    if (s == 0) {
#pragma unroll
        for (int k = 0; k < 2; ++k) {
            int r = tid + k * 256;
            g_boxes[(size_t)b * TILE + r] = box[r];
        }
    }

    const int rbase = s * 32;
#pragma unroll
    for (int k = 0; k < 2; ++k) {
        int idx = tid + k * 256;
        int row = rbase + (idx & 31);
        int w   = idx >> 5;
        int jbase = w << 5;
        float4 bi = box[row];
        float  ai = area_of(bi);
        uint32_t bits = 0u;
        if (jbase + 31 > row) {
#pragma unroll
            for (int c = 0; c < 32; ++c) {
                int j = jbase + c;
                float4 bj = box[j];
                float  aj = area_of(bj);
                bool gt = (j > row) & iou_gt(bi, ai, bj, aj);  // branchless
                bits |= ((uint32_t)gt) << c;
            }
        }
        g_supmat[((size_t)b * TILE + row) * 16 + w] = bits;
    }

    if (s < 8 && tid < 128) {
        int q  = s;
        int j  = tid >> 1;
        int w2 = tid & 1;
        int C  = q * 64 + j;
        float4 bc = box[C];
        float  ac = area_of(bc);
        uint32_t bits = 0u;
#pragma unroll
        for (int c = 0; c < 32; ++c) {
            int R = q * 64 + w2 * 32 + c;
            float4 br = box[R];
            float  ar = area_of(br);
            bool gt = (R < C) & iou_gt(br, ar, bc, ac);
            bits |= ((uint32_t)gt) << c;
        }
        g_supT[((size_t)b * TILE + C) * 2 + w2] = bits;
    }
}

// ---------------- K5: ballot-resolve chunked greedy sweep ------------------
__global__ __launch_bounds__(64) void k5_sweep(
    const uint32_t* __restrict__ g_supmat,
    const u64*    __restrict__ g_supT64,   // [B*512] diag col-words
    const u64*    __restrict__ g_sorted,   // fallback decode source
    const float4* __restrict__ deltas,
    const float4* __restrict__ anchors,
    const float4* __restrict__ g_boxes,    // [B*512]
    float4* __restrict__ out,
    int N)
{
    const int b    = blockIdx.x;
    const int lane = threadIdx.x;

    __shared__ uint32_t kept[POST];
    __shared__ u64 sh_keepbits[TILE / 64];
    __shared__ int sh_kc;
    // fallback-only LDS (untouched on the common path)
    __shared__ float4 fbox[PRE];
    __shared__ float  farea[PRE];
    __shared__ uint32_t fmask[(PRE - TILE + 31) / 32];

    const u64* tdbase = g_supT64 + (size_t)b * TILE;

    uint32_t removedw = 0u;              // lanes 0..15: removed word
    int kc = 0, nq = 0;
    u64 cw_cur = tdbase[lane];
    for (int q = 0; q < TILE / 64; ++q) {
        u64 cw_next = (q < TILE / 64 - 1) ? tdbase[(q + 1) * 64 + lane] : 0ull;
        const int cbase = q << 6;
        uint32_t rlo = (uint32_t)__builtin_amdgcn_readlane((int)removedw, 2 * q);
        uint32_t rhi = (uint32_t)__builtin_amdgcn_readlane((int)removedw, 2 * q + 1);
        u64 avail = ~(((u64)rhi << 32) | rlo);
        u64 K = 0ull;
        while (avail) {                  // ballot-based greedy resolve
            int i = __ffsll((long long)avail) - 1;
            K |= (1ull << i);
            u64 supp = __ballot(((cw_cur >> i) & 1ull) != 0ull);
            avail &= ~(supp | (1ull << i));
        }
        if (lane == 0) sh_keepbits[q] = K;
        kc += __popcll(K);
        nq = q + 1;
        if (kc >= POST) break;
        if (K) {                         // masked pipelined propagation
            const int w = lane & 15;
            const int g = lane >> 4;
            const uint32_t* gs =
                g_supmat + ((size_t)b * TILE + cbase + g * 16) * 16 + w;
            uint32_t acc = 0u;
#pragma unroll
            for (int r = 0; r < 16; ++r) {
                uint32_t v = gs[(size_t)r * 16];
                uint32_t m = (uint32_t)0 - (uint32_t)((K >> (g * 16 + r)) & 1ull);
                acc |= (v & m);
            }
            acc |= (uint32_t)__shfl_xor((int)acc, 16, 64);
            acc |= (uint32_t)__shfl_xor((int)acc, 32, 64);
            if (lane < 16) removedw |= acc;
        }
        cw_cur = cw_next;
    }
    {
        int base = 0;
        for (int q = 0; q < nq; ++q) {
            u64 kbq = sh_keepbits[q];
            int pos = base + __popcll(kbq & ((1ull << lane) - 1));
            if (((kbq >> lane) & 1ull) && pos < POST)
                kept[pos] = (uint32_t)(q * 64 + lane);
            base += __popcll(kbq);
        }
        if (lane == 0) sh_kc = min(kc, POST);
    }
    __syncthreads();
    int kcf = sh_kc;
    const bool fellback = (kcf < POST);

    if (fellback) {
        // exact continuation (never taken on this data): decode everything
        const float4* dl = deltas + (size_t)b * N;
        for (int r = lane; r < PRE; r += 64) {
            float4 bx = decode_key(g_sorted[(size_t)b * SORTN + r], dl,
                                   anchors, N);
            fbox[r]  = bx;
            farea[r] = area_of(bx);
        }
        for (int w = lane; w < (PRE - TILE + 31) / 32; w += 64) fmask[w] = 0u;
        __syncthreads();
        for (int j = TILE + lane; j < PRE; j += 64) {
            float4 bj = fbox[j];
            float  aj = farea[j];
            bool supd = false;
            for (int k = 0; k < kcf; ++k) {
                int i = (int)kept[k];
                if (iou_gt(fbox[i], farea[i], bj, aj)) { supd = true; break; }
            }
            if (supd) atomicOr(&fmask[(j - TILE) >> 5], 1u << ((j - TILE) & 31));
        }
        __syncthreads();
        int i = TILE;
        while (i < PRE && kcf < POST) {
            while (i < PRE && ((fmask[(i - TILE) >> 5] >> ((i - TILE) & 31)) & 1u)) ++i;
            if (i >= PRE) break;
            if (lane == 0) kept[kcf] = (uint32_t)i;
            ++kcf;
            if (kcf >= POST) break;
            float4 bi = fbox[i];
            float  ai = farea[i];
            for (int j = i + 1 + lane; j < PRE; j += 64) {
                if (iou_gt(bi, ai, fbox[j], farea[j]))
                    atomicOr(&fmask[(j - TILE) >> 5], 1u << ((j - TILE) & 31));
            }
            ++i;
            __syncthreads();
        }
    }
    __syncthreads();

    float4* ob = out + (size_t)b * POST;
    for (int r = lane; r < POST; r += 64) {
        float4 o = make_float4(0.f, 0.f, 0.f, 0.f);
        if (r < kcf) {
            int ki = (int)kept[r];
            float4 bx = fellback ? fbox[ki]
                                 : g_boxes[(size_t)b * TILE + ki];
            o.x = fminf(fmaxf(bx.x, 0.f), 1.f);
            o.y = fminf(fmaxf(bx.y, 0.f), 1.f);
            o.z = fminf(fmaxf(bx.z, 0.f), 1.f);
            o.w = fminf(fmaxf(bx.w, 0.f), 1.f);
        }
        ob[r] = o;
    }
}

extern "C" void kernel_launch(void* const* d_in, const int* in_sizes, int n_in,
                              void* d_out, int out_size, void* d_ws, size_t ws_size,
                              hipStream_t stream) {
    const float4* deltas  = (const float4*)d_in[0];
    const float*  labels  = (const float*)d_in[1];
    const float4* anchors = (const float4*)d_in[2];
    const float4* score4  = (const float4*)labels;
    float4*       outp    = (float4*)d_out;
    const int N = in_sizes[2] / 4;      // 90000
    const int B = in_sizes[1] / N;      // 64

    // workspace (16B-aligned chunks), no zero-init required anywhere:
    // boxes | pairs | sorted | supmat | supT | shist | scnt
    char* ws = (char*)d_ws;
    const size_t SZ_BOXES  = (size_t)B * TILE * 16;
    const size_t SZ_PAIRS  = (size_t)B * SL * KBUF * 8;
    const size_t SZ_SORTED = (size_t)B * SORTN * 8;
    const size_t SZ_SUPMAT = (size_t)B * TILE * 16 * 4;
    const size_t SZ_SUPT   = (size_t)B * TILE * 8;
    const size_t SZ_SHIST  = (size_t)B * SL * 64 * 4;
    float4*   g_boxes  = (float4*)ws;
    u64*      g_pairs  = (u64*)(ws + SZ_BOXES);
    u64*      g_sorted = (u64*)(ws + SZ_BOXES + SZ_PAIRS);
    uint32_t* g_supmat = (uint32_t*)(ws + SZ_BOXES + SZ_PAIRS + SZ_SORTED);
    uint32_t* g_supT   = (uint32_t*)(ws + SZ_BOXES + SZ_PAIRS + SZ_SORTED + SZ_SUPMAT);
    uint32_t* g_shist  = (uint32_t*)(ws + SZ_BOXES + SZ_PAIRS + SZ_SORTED + SZ_SUPMAT + SZ_SUPT);
    int*      g_scnt   = (int*)((char*)g_shist + SZ_SHIST);

    k1_gather<<<B * SL, 256, 0, stream>>>(score4, g_pairs, g_scnt, g_shist, N);
    k2_sort<<<B, 1024, 0, stream>>>(score4, g_pairs, g_scnt, g_shist,
                                    g_sorted, N);
    k4_supmat<<<B * 16, 256, 0, stream>>>(deltas, anchors, g_sorted,
                                          g_boxes, g_supmat, g_supT, N);
    k5_sweep<<<B, 64, 0, stream>>>(g_supmat, (const u64*)g_supT, g_sorted,
                                   deltas, anchors, g_boxes, outp, N);
}